// Round 1
// baseline (900.405 us; speedup 1.0000x reference)
//
#include <hip/hip_runtime.h>
#include <hip/hip_bf16.h>
#include <math.h>

typedef __bf16 bf16_t;
typedef bf16_t bf16x8 __attribute__((ext_vector_type(8)));
typedef bf16_t bf16x4 __attribute__((ext_vector_type(4)));
typedef float f32x4 __attribute__((ext_vector_type(4)));

#define D_MODEL 1024
#define SEQ     4096
#define BATCH   4
#define NTOK    16384   // BATCH*SEQ
#define DFF     4096
#define CLEN    64      // scan chunk length
#define NCHUNK  64      // chunks per sequence (CLEN*NCHUNK == SEQ)
#define NCH     4096    // channels = BATCH*D_MODEL

// ---------------------------------------------------------------------------
// Transpose fp32 [R][C] -> bf16 [C][R]
// ---------------------------------------------------------------------------
__global__ void transpose_to_bf16(const float* __restrict__ W,
                                  bf16_t* __restrict__ Wt, int R, int C) {
    __shared__ float tile[32][33];
    const int c0 = blockIdx.x * 32, r0 = blockIdx.y * 32;
    const int tx = threadIdx.x, ty = threadIdx.y;
#pragma unroll
    for (int j = 0; j < 32; j += 8)
        tile[ty + j][tx] = W[(size_t)(r0 + ty + j) * C + c0 + tx];
    __syncthreads();
#pragma unroll
    for (int j = 0; j < 32; j += 8)
        Wt[(size_t)(c0 + ty + j) * R + r0 + tx] = (bf16_t)tile[tx][ty + j];
}

// ---------------------------------------------------------------------------
// RMSNorm: fp32 [rows][1024] -> bf16 [rows][1024]   (block = 256 thr per row)
// ---------------------------------------------------------------------------
__global__ void rmsnorm_kernel(const float* __restrict__ x,
                               const float* __restrict__ w,
                               bf16_t* __restrict__ out) {
    const int row = blockIdx.x;
    const int tid = threadIdx.x;
    const float4 v = ((const float4*)(x + (size_t)row * D_MODEL))[tid];
    float ss = v.x * v.x + v.y * v.y + v.z * v.z + v.w * v.w;
#pragma unroll
    for (int o = 1; o < 64; o <<= 1) ss += __shfl_xor(ss, o);
    __shared__ float red[4];
    if ((tid & 63) == 0) red[tid >> 6] = ss;
    __syncthreads();
    const float tot = red[0] + red[1] + red[2] + red[3];
    const float scale = rsqrtf(tot * (1.0f / D_MODEL) + 1e-6f);
    const float4 wv = ((const float4*)w)[tid];
    bf16x4 o4;
    o4[0] = (bf16_t)(v.x * scale * wv.x);
    o4[1] = (bf16_t)(v.y * scale * wv.y);
    o4[2] = (bf16_t)(v.z * scale * wv.z);
    o4[3] = (bf16_t)(v.w * scale * wv.w);
    ((bf16x4*)(out + (size_t)row * D_MODEL))[tid] = o4;
}

// ---------------------------------------------------------------------------
// Dual-B GEMM, 128x128 tile, 4 waves, BK=32, mfma_f32_16x16x32_bf16.
// A: bf16 [M][K] row-major; B1t/B2t: bf16 [N][K] (i.e. W transposed).
// MODE 0: O1 = sigmoid(A@B1 + bias1), O2 = tanh(A@B2 + bias2)   (fp32)
// MODE 1: Ot = silu(A@B1) * (A@B2)                              (bf16)
// ---------------------------------------------------------------------------
template <int MODE>
__global__ __launch_bounds__(256, 2)
void gemm_dual(const bf16_t* __restrict__ A, const bf16_t* __restrict__ B1t,
               const bf16_t* __restrict__ B2t, const float* __restrict__ bias1,
               const float* __restrict__ bias2, float* __restrict__ O1,
               float* __restrict__ O2, bf16_t* __restrict__ Ot, int N, int K) {
    __shared__ bf16_t As[128][40];
    __shared__ bf16_t B1s[128][40];
    __shared__ bf16_t B2s[128][40];
    const int tid = threadIdx.x;
    const int bn = blockIdx.x, bm = blockIdx.y;
    const int sRow = tid >> 1, sCol = (tid & 1) << 4;
    const bf16_t* Ag  = A   + (size_t)(bm * 128 + sRow) * K + sCol;
    const bf16_t* B1g = B1t + (size_t)(bn * 128 + sRow) * K + sCol;
    const bf16_t* B2g = B2t + (size_t)(bn * 128 + sRow) * K + sCol;
    const int lane = tid & 63;
    const int wr = (tid >> 7) & 1, wc = (tid >> 6) & 1;
    const int lr = lane & 15, lk = lane >> 4;

    f32x4 acc1[4][4] = {};
    f32x4 acc2[4][4] = {};
    for (int k0 = 0; k0 < K; k0 += 32) {
        bf16x8 a0  = *(const bf16x8*)(Ag + k0);
        bf16x8 a1  = *(const bf16x8*)(Ag + k0 + 8);
        bf16x8 b10 = *(const bf16x8*)(B1g + k0);
        bf16x8 b11 = *(const bf16x8*)(B1g + k0 + 8);
        bf16x8 b20 = *(const bf16x8*)(B2g + k0);
        bf16x8 b21 = *(const bf16x8*)(B2g + k0 + 8);
        __syncthreads();
        *(bf16x8*)&As[sRow][sCol]      = a0;
        *(bf16x8*)&As[sRow][sCol + 8]  = a1;
        *(bf16x8*)&B1s[sRow][sCol]     = b10;
        *(bf16x8*)&B1s[sRow][sCol + 8] = b11;
        *(bf16x8*)&B2s[sRow][sCol]     = b20;
        *(bf16x8*)&B2s[sRow][sCol + 8] = b21;
        __syncthreads();
        bf16x8 af[4], b1f[4], b2f[4];
#pragma unroll
        for (int m = 0; m < 4; ++m)
            af[m] = *(const bf16x8*)&As[wr * 64 + m * 16 + lr][lk * 8];
#pragma unroll
        for (int n = 0; n < 4; ++n) {
            b1f[n] = *(const bf16x8*)&B1s[wc * 64 + n * 16 + lr][lk * 8];
            b2f[n] = *(const bf16x8*)&B2s[wc * 64 + n * 16 + lr][lk * 8];
        }
#pragma unroll
        for (int m = 0; m < 4; ++m)
#pragma unroll
            for (int n = 0; n < 4; ++n) {
                acc1[m][n] = __builtin_amdgcn_mfma_f32_16x16x32_bf16(
                    af[m], b1f[n], acc1[m][n], 0, 0, 0);
                acc2[m][n] = __builtin_amdgcn_mfma_f32_16x16x32_bf16(
                    af[m], b2f[n], acc2[m][n], 0, 0, 0);
            }
    }
    const int rowBase = bm * 128 + wr * 64;
    const int colBase = bn * 128 + wc * 64;
#pragma unroll
    for (int n = 0; n < 4; ++n) {
        const int col = colBase + n * 16 + lr;
        float b1v = 0.f, b2v = 0.f;
        if (MODE == 0) { b1v = bias1[col]; b2v = bias2[col]; }
#pragma unroll
        for (int m = 0; m < 4; ++m) {
#pragma unroll
            for (int j = 0; j < 4; ++j) {
                const int row = rowBase + m * 16 + lk * 4 + j;
                const size_t idx = (size_t)row * N + col;
                if (MODE == 0) {
                    const float gv = 1.0f / (1.0f + __expf(-(acc1[m][n][j] + b1v)));
                    const float cv = tanhf(acc2[m][n][j] + b2v);
                    O1[idx] = gv;
                    O2[idx] = cv;
                } else {
                    const float a = acc1[m][n][j];
                    const float s = a / (1.0f + __expf(-a));
                    Ot[idx] = (bf16_t)(s * acc2[m][n][j]);
                }
            }
        }
    }
}

// ---------------------------------------------------------------------------
// Single-B GEMM with in-place residual add: O[idx] += A@Bt   (O prewritten)
// ---------------------------------------------------------------------------
__global__ __launch_bounds__(256, 2)
void gemm_res(const bf16_t* __restrict__ A, const bf16_t* __restrict__ Bt,
              float* O, int N, int K) {
    __shared__ bf16_t As[128][40];
    __shared__ bf16_t Bs[128][40];
    const int tid = threadIdx.x;
    const int bn = blockIdx.x, bm = blockIdx.y;
    const int sRow = tid >> 1, sCol = (tid & 1) << 4;
    const bf16_t* Ag = A  + (size_t)(bm * 128 + sRow) * K + sCol;
    const bf16_t* Bg = Bt + (size_t)(bn * 128 + sRow) * K + sCol;
    const int lane = tid & 63;
    const int wr = (tid >> 7) & 1, wc = (tid >> 6) & 1;
    const int lr = lane & 15, lk = lane >> 4;

    f32x4 acc[4][4] = {};
    for (int k0 = 0; k0 < K; k0 += 32) {
        bf16x8 a0 = *(const bf16x8*)(Ag + k0);
        bf16x8 a1 = *(const bf16x8*)(Ag + k0 + 8);
        bf16x8 b0 = *(const bf16x8*)(Bg + k0);
        bf16x8 b1 = *(const bf16x8*)(Bg + k0 + 8);
        __syncthreads();
        *(bf16x8*)&As[sRow][sCol]     = a0;
        *(bf16x8*)&As[sRow][sCol + 8] = a1;
        *(bf16x8*)&Bs[sRow][sCol]     = b0;
        *(bf16x8*)&Bs[sRow][sCol + 8] = b1;
        __syncthreads();
        bf16x8 af[4], bf[4];
#pragma unroll
        for (int m = 0; m < 4; ++m)
            af[m] = *(const bf16x8*)&As[wr * 64 + m * 16 + lr][lk * 8];
#pragma unroll
        for (int n = 0; n < 4; ++n)
            bf[n] = *(const bf16x8*)&Bs[wc * 64 + n * 16 + lr][lk * 8];
#pragma unroll
        for (int m = 0; m < 4; ++m)
#pragma unroll
            for (int n = 0; n < 4; ++n)
                acc[m][n] = __builtin_amdgcn_mfma_f32_16x16x32_bf16(
                    af[m], bf[n], acc[m][n], 0, 0, 0);
    }
    const int rowBase = bm * 128 + wr * 64;
    const int colBase = bn * 128 + wc * 64;
#pragma unroll
    for (int n = 0; n < 4; ++n) {
        const int col = colBase + n * 16 + lr;
#pragma unroll
        for (int m = 0; m < 4; ++m) {
#pragma unroll
            for (int j = 0; j < 4; ++j) {
                const int row = rowBase + m * 16 + lk * 4 + j;
                const size_t idx = (size_t)row * N + col;
                O[idx] += acc[m][n][j];
            }
        }
    }
}

// ---------------------------------------------------------------------------
// MinGRU scan: h_t = g_t * h_{t-1} + (1-g_t)*c_t, chunked 3-phase.
// Layout of g/c: [BATCH][SEQ][D_MODEL].
// ---------------------------------------------------------------------------
__global__ void scan_phase1(const float* __restrict__ g,
                            const float* __restrict__ c,
                            float* __restrict__ cA, float* __restrict__ cB) {
    const int d = blockIdx.x * 256 + threadIdx.x;
    const int b = blockIdx.y;
    const int cidx = blockIdx.z;
    const int ch = b * D_MODEL + d;
    const size_t base = ((size_t)b * SEQ + (size_t)cidx * CLEN) * D_MODEL + d;
    float A = 1.0f, Bv = 0.0f;
#pragma unroll 4
    for (int t = 0; t < CLEN; ++t) {
        const float gv = g[base + (size_t)t * D_MODEL];
        const float cv = c[base + (size_t)t * D_MODEL];
        Bv = gv * Bv + (1.0f - gv) * cv;
        A *= gv;
    }
    cA[cidx * NCH + ch] = A;
    cB[cidx * NCH + ch] = Bv;
}

__global__ void scan_phase2(const float* __restrict__ cA,
                            const float* __restrict__ cB,
                            float* __restrict__ hstart) {
    const int ch = blockIdx.x * 256 + threadIdx.x;
    float h = 0.0f;
    for (int cdx = 0; cdx < NCHUNK; ++cdx) {
        hstart[cdx * NCH + ch] = h;
        h = cA[cdx * NCH + ch] * h + cB[cdx * NCH + ch];
    }
}

__global__ void scan_phase3(const float* __restrict__ g,
                            const float* __restrict__ c,
                            const float* __restrict__ hstart,
                            const float* __restrict__ x,
                            float* __restrict__ x1) {
    const int d = blockIdx.x * 256 + threadIdx.x;
    const int b = blockIdx.y;
    const int cidx = blockIdx.z;
    const int ch = b * D_MODEL + d;
    const size_t base = ((size_t)b * SEQ + (size_t)cidx * CLEN) * D_MODEL + d;
    float h = hstart[cidx * NCH + ch];
#pragma unroll 4
    for (int t = 0; t < CLEN; ++t) {
        const size_t off = base + (size_t)t * D_MODEL;
        const float gv = g[off];
        const float cv = c[off];
        h = gv * h + (1.0f - gv) * cv;
        x1[off] = x[off] + h;
    }
}

// ---------------------------------------------------------------------------
extern "C" void kernel_launch(void* const* d_in, const int* in_sizes, int n_in,
                              void* d_out, int out_size, void* d_ws,
                              size_t ws_size, hipStream_t stream) {
    const float* x   = (const float*)d_in[0];
    const float* Wg  = (const float*)d_in[1];
    const float* bg  = (const float*)d_in[2];
    const float* Wc  = (const float*)d_in[3];
    const float* bc  = (const float*)d_in[4];
    const float* n1w = (const float*)d_in[5];
    const float* n2w = (const float*)d_in[6];
    const float* W1  = (const float*)d_in[7];
    const float* W3  = (const float*)d_in[8];
    const float* W2  = (const float*)d_in[9];
    float* out = (float*)d_out;

    char* p = (char*)d_ws;
    bf16_t* h_in = (bf16_t*)p;  p += (size_t)NTOK * D_MODEL * 2;
    bf16_t* f_in = (bf16_t*)p;  p += (size_t)NTOK * D_MODEL * 2;
    bf16_t* Wg_t = (bf16_t*)p;  p += (size_t)D_MODEL * D_MODEL * 2;
    bf16_t* Wc_t = (bf16_t*)p;  p += (size_t)D_MODEL * D_MODEL * 2;
    bf16_t* W1_t = (bf16_t*)p;  p += (size_t)DFF * D_MODEL * 2;
    bf16_t* W3_t = (bf16_t*)p;  p += (size_t)DFF * D_MODEL * 2;
    bf16_t* W2_t = (bf16_t*)p;  p += (size_t)D_MODEL * DFF * 2;
    float* cA     = (float*)p;  p += (size_t)NCHUNK * NCH * 4;
    float* cB     = (float*)p;  p += (size_t)NCHUNK * NCH * 4;
    float* hstart = (float*)p;  p += (size_t)NCHUNK * NCH * 4;
    float* gbuf   = (float*)p;  p += (size_t)NTOK * D_MODEL * 4;
    float* cbuf   = (float*)p;  p += (size_t)NTOK * D_MODEL * 4;
    bf16_t* tbuf  = (bf16_t*)gbuf;  // reuse: NTOK*DFF*2 == NTOK*D_MODEL*8 bytes

    const dim3 tb(32, 8);
    // weight transposes (fp32 [R][C] -> bf16 [C][R])
    transpose_to_bf16<<<dim3(1024 / 32, 1024 / 32), tb, 0, stream>>>(Wg, Wg_t, 1024, 1024);
    transpose_to_bf16<<<dim3(1024 / 32, 1024 / 32), tb, 0, stream>>>(Wc, Wc_t, 1024, 1024);
    transpose_to_bf16<<<dim3(4096 / 32, 1024 / 32), tb, 0, stream>>>(W1, W1_t, 1024, 4096);
    transpose_to_bf16<<<dim3(4096 / 32, 1024 / 32), tb, 0, stream>>>(W3, W3_t, 1024, 4096);
    transpose_to_bf16<<<dim3(1024 / 32, 4096 / 32), tb, 0, stream>>>(W2, W2_t, 4096, 1024);

    // 1) h_in = rmsnorm(x, n1_w)  (bf16)
    rmsnorm_kernel<<<NTOK, 256, 0, stream>>>(x, n1w, h_in);

    // 2) g = sigmoid(h_in@Wg + bg), c = tanh(h_in@Wc + bc)
    gemm_dual<0><<<dim3(D_MODEL / 128, NTOK / 128), 256, 0, stream>>>(
        h_in, Wg_t, Wc_t, bg, bc, gbuf, cbuf, nullptr, D_MODEL, D_MODEL);

    // 3) chunked scan; phase3 writes x1 = x + h into d_out
    scan_phase1<<<dim3(D_MODEL / 256, BATCH, NCHUNK), 256, 0, stream>>>(gbuf, cbuf, cA, cB);
    scan_phase2<<<NCH / 256, 256, 0, stream>>>(cA, cB, hstart);
    scan_phase3<<<dim3(D_MODEL / 256, BATCH, NCHUNK), 256, 0, stream>>>(gbuf, cbuf, hstart, x, out);

    // 4) f_in = rmsnorm(x1, n2_w)
    rmsnorm_kernel<<<NTOK, 256, 0, stream>>>(out, n2w, f_in);

    // 5) t = silu(f_in@W1) * (f_in@W3)  (bf16)
    gemm_dual<1><<<dim3(DFF / 128, NTOK / 128), 256, 0, stream>>>(
        f_in, W1_t, W3_t, nullptr, nullptr, nullptr, nullptr, tbuf, DFF, D_MODEL);

    // 6) out = x1 + t@W2  (in-place on d_out)
    gemm_res<<<dim3(D_MODEL / 128, NTOK / 128), 256, 0, stream>>>(tbuf, W2_t, out, D_MODEL, DFF);
}

// Round 2
// 847.934 us; speedup vs baseline: 1.0619x; 1.0619x over previous
//
#include <hip/hip_runtime.h>
#include <hip/hip_bf16.h>
#include <math.h>

typedef __bf16 bf16_t;
typedef bf16_t bf16x8 __attribute__((ext_vector_type(8)));
typedef bf16_t bf16x4 __attribute__((ext_vector_type(4)));
typedef bf16_t bf16x2 __attribute__((ext_vector_type(2)));
typedef float f32x4 __attribute__((ext_vector_type(4)));

#define D_MODEL 1024
#define SEQ     4096
#define BATCH   4
#define NTOK    16384   // BATCH*SEQ
#define DFF     4096
#define CLEN    64      // scan chunk length
#define NCHUNK  64      // chunks per sequence (CLEN*NCHUNK == SEQ)
#define NCH     4096    // channels = BATCH*D_MODEL

// async global->LDS, 16B per lane; LDS dest is wave-uniform base + lane*16
__device__ __forceinline__ void gload16(const bf16_t* g, bf16_t* l) {
    __builtin_amdgcn_global_load_lds(
        (const __attribute__((address_space(1))) void*)g,
        (__attribute__((address_space(3))) void*)l, 16, 0, 0);
}

// ---------------------------------------------------------------------------
// Transpose fp32 [R][C] -> bf16 [C][R]
// ---------------------------------------------------------------------------
__global__ void transpose_to_bf16(const float* __restrict__ W,
                                  bf16_t* __restrict__ Wt, int R, int C) {
    __shared__ float tile[32][33];
    const int c0 = blockIdx.x * 32, r0 = blockIdx.y * 32;
    const int tx = threadIdx.x, ty = threadIdx.y;
#pragma unroll
    for (int j = 0; j < 32; j += 8)
        tile[ty + j][tx] = W[(size_t)(r0 + ty + j) * C + c0 + tx];
    __syncthreads();
#pragma unroll
    for (int j = 0; j < 32; j += 8)
        Wt[(size_t)(c0 + ty + j) * R + r0 + tx] = (bf16_t)tile[tx][ty + j];
}

// ---------------------------------------------------------------------------
// RMSNorm: fp32 [rows][1024] -> bf16 [rows][1024]   (block = 256 thr per row)
// ---------------------------------------------------------------------------
__global__ void rmsnorm_kernel(const float* __restrict__ x,
                               const float* __restrict__ w,
                               bf16_t* __restrict__ out) {
    const int row = blockIdx.x;
    const int tid = threadIdx.x;
    const float4 v = ((const float4*)(x + (size_t)row * D_MODEL))[tid];
    float ss = v.x * v.x + v.y * v.y + v.z * v.z + v.w * v.w;
#pragma unroll
    for (int o = 1; o < 64; o <<= 1) ss += __shfl_xor(ss, o);
    __shared__ float red[4];
    if ((tid & 63) == 0) red[tid >> 6] = ss;
    __syncthreads();
    const float tot = red[0] + red[1] + red[2] + red[3];
    const float scale = rsqrtf(tot * (1.0f / D_MODEL) + 1e-6f);
    const float4 wv = ((const float4*)w)[tid];
    bf16x4 o4;
    o4[0] = (bf16_t)(v.x * scale * wv.x);
    o4[1] = (bf16_t)(v.y * scale * wv.y);
    o4[2] = (bf16_t)(v.z * scale * wv.z);
    o4[3] = (bf16_t)(v.w * scale * wv.w);
    ((bf16x4*)(out + (size_t)row * D_MODEL))[tid] = o4;
}

// ---------------------------------------------------------------------------
// Dual-B GEMM, 128x128 tile, 4 waves, BK=32, mfma_f32_16x16x32_bf16,
// global_load_lds staging (m97 structure), linear LDS [128][32].
// A: bf16 [M][K] row-major; B1t/B2t: bf16 [N][K] (W transposed).
// MODE 0: GC[idx] = {sigmoid(A@B1+bias1), tanh(A@B2+bias2)} packed bf16x2
// MODE 1: Ot[idx] = silu(A@B1) * (A@B2)                       (bf16)
// ---------------------------------------------------------------------------
template <int MODE>
__global__ __launch_bounds__(256, 2)
void gemm_dual(const bf16_t* __restrict__ A, const bf16_t* __restrict__ B1t,
               const bf16_t* __restrict__ B2t, const float* __restrict__ bias1,
               const float* __restrict__ bias2, bf16x2* __restrict__ GC,
               bf16_t* __restrict__ Ot, int N, int K) {
    __shared__ bf16_t As[128 * 32];
    __shared__ bf16_t B1s[128 * 32];
    __shared__ bf16_t B2s[128 * 32];
    const int tid = threadIdx.x;
    const int lane = tid & 63;
    const int wave = tid >> 6;                 // 0..3
    const int bn = blockIdx.x, bm = blockIdx.y;

    // staging: wave w, instr i covers LDS rows [i*64 + w*16, +16), 16B/lane
    const int stR = wave * 16 + (lane >> 2);   // chunk-relative row 0..63
    const int stC = (lane & 3) * 8;
    const bf16_t* Ag  = A   + (size_t)(bm * 128 + stR) * K + stC;
    const bf16_t* B1g = B1t + (size_t)(bn * 128 + stR) * K + stC;
    const bf16_t* B2g = B2t + (size_t)(bn * 128 + stR) * K + stC;
    bf16_t* Al0  = &As [(wave * 16) * 32];
    bf16_t* Al1  = &As [(64 + wave * 16) * 32];
    bf16_t* B1l0 = &B1s[(wave * 16) * 32];
    bf16_t* B1l1 = &B1s[(64 + wave * 16) * 32];
    bf16_t* B2l0 = &B2s[(wave * 16) * 32];
    bf16_t* B2l1 = &B2s[(64 + wave * 16) * 32];
    const size_t row64 = (size_t)64 * K;

    const int wr = wave >> 1, wc = wave & 1;
    const int lr = lane & 15, lk = lane >> 4;

    f32x4 acc1[4][4] = {};
    f32x4 acc2[4][4] = {};
    for (int k0 = 0; k0 < K; k0 += 32) {
        __syncthreads();                       // prev-tile reads done
        gload16(Ag  + k0,         Al0);
        gload16(Ag  + k0 + row64, Al1);
        gload16(B1g + k0,         B1l0);
        gload16(B1g + k0 + row64, B1l1);
        gload16(B2g + k0,         B2l0);
        gload16(B2g + k0 + row64, B2l1);
        __syncthreads();                       // vmcnt(0) drained -> LDS ready
        bf16x8 af[4], b1f[4], b2f[4];
#pragma unroll
        for (int m = 0; m < 4; ++m)
            af[m] = *(const bf16x8*)&As[(wr * 64 + m * 16 + lr) * 32 + lk * 8];
#pragma unroll
        for (int n = 0; n < 4; ++n) {
            b1f[n] = *(const bf16x8*)&B1s[(wc * 64 + n * 16 + lr) * 32 + lk * 8];
            b2f[n] = *(const bf16x8*)&B2s[(wc * 64 + n * 16 + lr) * 32 + lk * 8];
        }
#pragma unroll
        for (int m = 0; m < 4; ++m)
#pragma unroll
            for (int n = 0; n < 4; ++n) {
                acc1[m][n] = __builtin_amdgcn_mfma_f32_16x16x32_bf16(
                    af[m], b1f[n], acc1[m][n], 0, 0, 0);
                acc2[m][n] = __builtin_amdgcn_mfma_f32_16x16x32_bf16(
                    af[m], b2f[n], acc2[m][n], 0, 0, 0);
            }
    }
    const int rowBase = bm * 128 + wr * 64;
    const int colBase = bn * 128 + wc * 64;
#pragma unroll
    for (int n = 0; n < 4; ++n) {
        const int col = colBase + n * 16 + lr;
        float b1v = 0.f, b2v = 0.f;
        if (MODE == 0) { b1v = bias1[col]; b2v = bias2[col]; }
#pragma unroll
        for (int m = 0; m < 4; ++m) {
#pragma unroll
            for (int j = 0; j < 4; ++j) {
                const int row = rowBase + m * 16 + lk * 4 + j;
                const size_t idx = (size_t)row * N + col;
                if (MODE == 0) {
                    const float gv = 1.0f / (1.0f + __expf(-(acc1[m][n][j] + b1v)));
                    const float cv = tanhf(acc2[m][n][j] + b2v);
                    bf16x2 pk;
                    pk[0] = (bf16_t)gv;
                    pk[1] = (bf16_t)cv;
                    GC[idx] = pk;
                } else {
                    const float a = acc1[m][n][j];
                    const float s = a / (1.0f + __expf(-a));
                    Ot[idx] = (bf16_t)(s * acc2[m][n][j]);
                }
            }
        }
    }
}

// ---------------------------------------------------------------------------
// Single-B GEMM with in-place residual add: O[idx] += A@Bt   (O prewritten)
// ---------------------------------------------------------------------------
__global__ __launch_bounds__(256, 2)
void gemm_res(const bf16_t* __restrict__ A, const bf16_t* __restrict__ Bt,
              float* O, int N, int K) {
    __shared__ bf16_t As[128 * 32];
    __shared__ bf16_t Bs[128 * 32];
    const int tid = threadIdx.x;
    const int lane = tid & 63;
    const int wave = tid >> 6;
    const int bn = blockIdx.x, bm = blockIdx.y;

    const int stR = wave * 16 + (lane >> 2);
    const int stC = (lane & 3) * 8;
    const bf16_t* Ag = A  + (size_t)(bm * 128 + stR) * K + stC;
    const bf16_t* Bg = Bt + (size_t)(bn * 128 + stR) * K + stC;
    bf16_t* Al0 = &As[(wave * 16) * 32];
    bf16_t* Al1 = &As[(64 + wave * 16) * 32];
    bf16_t* Bl0 = &Bs[(wave * 16) * 32];
    bf16_t* Bl1 = &Bs[(64 + wave * 16) * 32];
    const size_t row64 = (size_t)64 * K;

    const int wr = wave >> 1, wc = wave & 1;
    const int lr = lane & 15, lk = lane >> 4;

    f32x4 acc[4][4] = {};
    for (int k0 = 0; k0 < K; k0 += 32) {
        __syncthreads();
        gload16(Ag + k0,         Al0);
        gload16(Ag + k0 + row64, Al1);
        gload16(Bg + k0,         Bl0);
        gload16(Bg + k0 + row64, Bl1);
        __syncthreads();
        bf16x8 af[4], bf[4];
#pragma unroll
        for (int m = 0; m < 4; ++m)
            af[m] = *(const bf16x8*)&As[(wr * 64 + m * 16 + lr) * 32 + lk * 8];
#pragma unroll
        for (int n = 0; n < 4; ++n)
            bf[n] = *(const bf16x8*)&Bs[(wc * 64 + n * 16 + lr) * 32 + lk * 8];
#pragma unroll
        for (int m = 0; m < 4; ++m)
#pragma unroll
            for (int n = 0; n < 4; ++n)
                acc[m][n] = __builtin_amdgcn_mfma_f32_16x16x32_bf16(
                    af[m], bf[n], acc[m][n], 0, 0, 0);
    }
    const int rowBase = bm * 128 + wr * 64;
    const int colBase = bn * 128 + wc * 64;
#pragma unroll
    for (int n = 0; n < 4; ++n) {
        const int col = colBase + n * 16 + lr;
#pragma unroll
        for (int m = 0; m < 4; ++m) {
#pragma unroll
            for (int j = 0; j < 4; ++j) {
                const int row = rowBase + m * 16 + lk * 4 + j;
                const size_t idx = (size_t)row * N + col;
                O[idx] += acc[m][n][j];
            }
        }
    }
}

// ---------------------------------------------------------------------------
// MinGRU scan: h_t = g_t*h_{t-1} + (1-g_t)*c_t, chunked 3-phase.
// gc: [BATCH][SEQ][D_MODEL] packed bf16x2 {g, c}.
// ---------------------------------------------------------------------------
__global__ void scan_phase1(const bf16x2* __restrict__ gc,
                            float* __restrict__ cA, float* __restrict__ cB) {
    const int d = blockIdx.x * 256 + threadIdx.x;
    const int b = blockIdx.y;
    const int cidx = blockIdx.z;
    const int ch = b * D_MODEL + d;
    const size_t base = ((size_t)b * SEQ + (size_t)cidx * CLEN) * D_MODEL + d;
    float A = 1.0f, Bv = 0.0f;
#pragma unroll 8
    for (int t = 0; t < CLEN; ++t) {
        const bf16x2 v = gc[base + (size_t)t * D_MODEL];
        const float gv = (float)v[0], cv = (float)v[1];
        Bv = gv * Bv + (1.0f - gv) * cv;
        A *= gv;
    }
    cA[cidx * NCH + ch] = A;
    cB[cidx * NCH + ch] = Bv;
}

__global__ void scan_phase2(const float* __restrict__ cA,
                            const float* __restrict__ cB,
                            float* __restrict__ hstart) {
    const int ch = blockIdx.x * 256 + threadIdx.x;
    float h = 0.0f;
#pragma unroll 8
    for (int cdx = 0; cdx < NCHUNK; ++cdx) {
        hstart[cdx * NCH + ch] = h;
        h = cA[cdx * NCH + ch] * h + cB[cdx * NCH + ch];
    }
}

__global__ void scan_phase3(const bf16x2* __restrict__ gc,
                            const float* __restrict__ hstart,
                            const float* __restrict__ x,
                            float* __restrict__ x1) {
    const int d = blockIdx.x * 256 + threadIdx.x;
    const int b = blockIdx.y;
    const int cidx = blockIdx.z;
    const int ch = b * D_MODEL + d;
    const size_t base = ((size_t)b * SEQ + (size_t)cidx * CLEN) * D_MODEL + d;
    float h = hstart[cidx * NCH + ch];
#pragma unroll 8
    for (int t = 0; t < CLEN; ++t) {
        const size_t off = base + (size_t)t * D_MODEL;
        const bf16x2 v = gc[off];
        const float gv = (float)v[0], cv = (float)v[1];
        h = gv * h + (1.0f - gv) * cv;
        x1[off] = x[off] + h;
    }
}

// ---------------------------------------------------------------------------
extern "C" void kernel_launch(void* const* d_in, const int* in_sizes, int n_in,
                              void* d_out, int out_size, void* d_ws,
                              size_t ws_size, hipStream_t stream) {
    const float* x   = (const float*)d_in[0];
    const float* Wg  = (const float*)d_in[1];
    const float* bg  = (const float*)d_in[2];
    const float* Wc  = (const float*)d_in[3];
    const float* bc  = (const float*)d_in[4];
    const float* n1w = (const float*)d_in[5];
    const float* n2w = (const float*)d_in[6];
    const float* W1  = (const float*)d_in[7];
    const float* W3  = (const float*)d_in[8];
    const float* W2  = (const float*)d_in[9];
    float* out = (float*)d_out;

    // Workspace layout (191 MB total; tbuf overlaps h_in+gcbuf+pad, all of
    // which are dead by the time the FFN dual GEMM writes tbuf):
    char* p = (char*)d_ws;
    bf16_t* tbuf  = (bf16_t*)p;                        // 128 MB [0,128)
    bf16_t* h_in  = (bf16_t*)p;  p += (size_t)NTOK * D_MODEL * 2;   // 32 MB
    bf16x2* gcbuf = (bf16x2*)p;  p += (size_t)NTOK * D_MODEL * 4;   // 64 MB
    p += (size_t)32 << 20;                             // pad (tail of tbuf)
    bf16_t* f_in  = (bf16_t*)p;  p += (size_t)NTOK * D_MODEL * 2;   // 32 MB
    bf16_t* Wg_t  = (bf16_t*)p;  p += (size_t)D_MODEL * D_MODEL * 2;
    bf16_t* Wc_t  = (bf16_t*)p;  p += (size_t)D_MODEL * D_MODEL * 2;
    bf16_t* W1_t  = (bf16_t*)p;  p += (size_t)DFF * D_MODEL * 2;
    bf16_t* W3_t  = (bf16_t*)p;  p += (size_t)DFF * D_MODEL * 2;
    bf16_t* W2_t  = (bf16_t*)p;  p += (size_t)D_MODEL * DFF * 2;
    float* cA     = (float*)p;   p += (size_t)NCHUNK * NCH * 4;
    float* cB     = (float*)p;   p += (size_t)NCHUNK * NCH * 4;
    float* hstart = (float*)p;   p += (size_t)NCHUNK * NCH * 4;

    const dim3 tb(32, 8);
    transpose_to_bf16<<<dim3(1024 / 32, 1024 / 32), tb, 0, stream>>>(Wg, Wg_t, 1024, 1024);
    transpose_to_bf16<<<dim3(1024 / 32, 1024 / 32), tb, 0, stream>>>(Wc, Wc_t, 1024, 1024);
    transpose_to_bf16<<<dim3(4096 / 32, 1024 / 32), tb, 0, stream>>>(W1, W1_t, 1024, 4096);
    transpose_to_bf16<<<dim3(4096 / 32, 1024 / 32), tb, 0, stream>>>(W3, W3_t, 1024, 4096);
    transpose_to_bf16<<<dim3(1024 / 32, 4096 / 32), tb, 0, stream>>>(W2, W2_t, 4096, 1024);

    // 1) h_in = rmsnorm(x, n1_w)  (bf16)
    rmsnorm_kernel<<<NTOK, 256, 0, stream>>>(x, n1w, h_in);

    // 2) gc = {sigmoid(h_in@Wg+bg), tanh(h_in@Wc+bc)} packed bf16x2
    gemm_dual<0><<<dim3(D_MODEL / 128, NTOK / 128), 256, 0, stream>>>(
        h_in, Wg_t, Wc_t, bg, bc, gcbuf, nullptr, D_MODEL, D_MODEL);

    // 3) chunked scan; phase3 writes x1 = x + h into d_out
    scan_phase1<<<dim3(D_MODEL / 256, BATCH, NCHUNK), 256, 0, stream>>>(gcbuf, cA, cB);
    scan_phase2<<<NCH / 256, 256, 0, stream>>>(cA, cB, hstart);
    scan_phase3<<<dim3(D_MODEL / 256, BATCH, NCHUNK), 256, 0, stream>>>(gcbuf, hstart, x, out);

    // 4) f_in = rmsnorm(x1, n2_w)
    rmsnorm_kernel<<<NTOK, 256, 0, stream>>>(out, n2w, f_in);

    // 5) t = silu(f_in@W1) * (f_in@W3)  (bf16)
    gemm_dual<1><<<dim3(DFF / 128, NTOK / 128), 256, 0, stream>>>(
        f_in, W1_t, W3_t, nullptr, nullptr, nullptr, tbuf, DFF, D_MODEL);

    // 6) out = x1 + t@W2  (in-place on d_out)
    gemm_res<<<dim3(D_MODEL / 128, NTOK / 128), 256, 0, stream>>>(tbuf, W2_t, out, D_MODEL, DFF);
}

// Round 3
// 765.111 us; speedup vs baseline: 1.1768x; 1.1082x over previous
//
#include <hip/hip_runtime.h>
#include <hip/hip_bf16.h>
#include <math.h>

typedef __bf16 bf16_t;
typedef bf16_t bf16x8 __attribute__((ext_vector_type(8)));
typedef bf16_t bf16x4 __attribute__((ext_vector_type(4)));
typedef bf16_t bf16x2 __attribute__((ext_vector_type(2)));
typedef float f32x4 __attribute__((ext_vector_type(4)));

#define D_MODEL 1024
#define SEQ     4096
#define BATCH   4
#define NTOK    16384   // BATCH*SEQ
#define DFF     4096
#define CLEN    64      // scan chunk length
#define NCHUNK  64      // chunks per sequence (CLEN*NCHUNK == SEQ)
#define NCH     4096    // channels = BATCH*D_MODEL

// async global->LDS, 16B per lane; LDS dest is wave-uniform base + lane*16
__device__ __forceinline__ void gload16(const bf16_t* g, bf16_t* l) {
    __builtin_amdgcn_global_load_lds(
        (const __attribute__((address_space(1))) void*)g,
        (__attribute__((address_space(3))) void*)l, 16, 0, 0);
}

// ---------------------------------------------------------------------------
// Transpose fp32 [R][C] -> bf16 [C][R]
// ---------------------------------------------------------------------------
__global__ void transpose_to_bf16(const float* __restrict__ W,
                                  bf16_t* __restrict__ Wt, int R, int C) {
    __shared__ float tile[32][33];
    const int c0 = blockIdx.x * 32, r0 = blockIdx.y * 32;
    const int tx = threadIdx.x, ty = threadIdx.y;
#pragma unroll
    for (int j = 0; j < 32; j += 8)
        tile[ty + j][tx] = W[(size_t)(r0 + ty + j) * C + c0 + tx];
    __syncthreads();
#pragma unroll
    for (int j = 0; j < 32; j += 8)
        Wt[(size_t)(c0 + ty + j) * R + r0 + tx] = (bf16_t)tile[tx][ty + j];
}

// ---------------------------------------------------------------------------
// RMSNorm: fp32 [rows][1024] -> bf16 [rows][1024]   (block = 256 thr per row)
// ---------------------------------------------------------------------------
__global__ void rmsnorm_kernel(const float* __restrict__ x,
                               const float* __restrict__ w,
                               bf16_t* __restrict__ out) {
    const int row = blockIdx.x;
    const int tid = threadIdx.x;
    const float4 v = ((const float4*)(x + (size_t)row * D_MODEL))[tid];
    float ss = v.x * v.x + v.y * v.y + v.z * v.z + v.w * v.w;
#pragma unroll
    for (int o = 1; o < 64; o <<= 1) ss += __shfl_xor(ss, o);
    __shared__ float red[4];
    if ((tid & 63) == 0) red[tid >> 6] = ss;
    __syncthreads();
    const float tot = red[0] + red[1] + red[2] + red[3];
    const float scale = rsqrtf(tot * (1.0f / D_MODEL) + 1e-6f);
    const float4 wv = ((const float4*)w)[tid];
    bf16x4 o4;
    o4[0] = (bf16_t)(v.x * scale * wv.x);
    o4[1] = (bf16_t)(v.y * scale * wv.y);
    o4[2] = (bf16_t)(v.z * scale * wv.z);
    o4[3] = (bf16_t)(v.w * scale * wv.w);
    ((bf16x4*)(out + (size_t)row * D_MODEL))[tid] = o4;
}

// ---------------------------------------------------------------------------
// 8-phase 256-row GEMM (m201-style schedule, plain HIP).
// BM=256, BK=64, 512 threads = 8 waves (2M x 4N).
//   MODE 0: dual-B BN=128, GC = {sigmoid(A@B1+b1), tanh(A@B2+b2)} bf16x2
//   MODE 1: dual-B BN=128, Ot = silu(A@B1) * (A@B2)   (bf16)
//   MODE 2: single-B BN=256, O += A@B                  (fp32, in-place)
// A: bf16 [M][K]; B*t: bf16 [N][K]. K % 64 == 0, grid % 8 == 0.
// LDS per buffer (32768 bf16): A tile 256x64 @0; B: dual 128x64 @16384 +
// 128x64 @24576; single 256x64 @16384. Double-buffered = 128 KiB.
// Swizzle: 16B chunk c of row r stored at slot c^(r&7) (2-way = free on
// ds_read_b128); staged via pre-swizzled per-lane GLOBAL address, linear
// LDS dest (global_load_lds constraint).
// ---------------------------------------------------------------------------
#define MFMA16(a, b, c) __builtin_amdgcn_mfma_f32_16x16x32_bf16((a), (b), (c), 0, 0, 0)

template <int MODE>
__global__ __launch_bounds__(512, 2)
void gemm8p(const bf16_t* __restrict__ A, const bf16_t* __restrict__ B1t,
            const bf16_t* __restrict__ B2t, const float* __restrict__ bias1,
            const float* __restrict__ bias2, bf16x2* __restrict__ GC,
            bf16_t* __restrict__ Ot, float* __restrict__ O,
            int N, int K, int lg_nbn) {
    constexpr bool DUAL = (MODE != 2);
    constexpr int BN = DUAL ? 128 : 256;
    constexpr int NFR = DUAL ? 2 : 4;     // n-fragments per wave
    __shared__ bf16_t lds[65536];         // 128 KiB

    const int tid = threadIdx.x;
    const int lane = tid & 63;
    const int wave = tid >> 6;            // 0..7
    const int wr = wave >> 2, wc = wave & 3;
    const int lr16 = lane & 15, lk = lane >> 4;

    // XCD-bijective block swizzle (gridDim.x % 8 == 0 for all our launches)
    const int nwg = gridDim.x;
    const int wg = blockIdx.x;
    const int swg = (wg & 7) * (nwg >> 3) + (wg >> 3);
    const int bn = swg & ((1 << lg_nbn) - 1);
    const int bm = swg >> lg_nbn;
    const int nt = K >> 6;

    // staging source (pre-swizzled chunk): lane l covers row (wave*8 + l>>3),
    // LDS chunk-slot l&7, which must hold global chunk (l&7)^(l>>3).
    const int lr8 = lane >> 3;
    const int cge = ((lane & 7) ^ lr8) << 3;   // element offset within row
    const bf16_t* Ag  = A   + (size_t)(bm * 256 + wave * 8 + lr8) * K + cge;
    const bf16_t* B1g = B1t + (size_t)(bn * BN  + wave * 8 + lr8) * K + cge;
    const bf16_t* B2g = DUAL ? (B2t + (size_t)(bn * BN + wave * 8 + lr8) * K + cge)
                             : (const bf16_t*)nullptr;

    f32x4 acc1[8][NFR] = {};
    f32x4 acc2[DUAL ? 8 : 1][NFR] = {};

    auto stageA = [&](int u) {   // full A tile of K-tile u (4 loads/thread)
        bf16_t* dst = &lds[(u & 1) * 32768 + wave * 512];
        const bf16_t* src = Ag + ((size_t)u << 6);
        gload16(src,                     dst);
        gload16(src + ((size_t)64  * K), dst + 4096);
        gload16(src + ((size_t)128 * K), dst + 8192);
        gload16(src + ((size_t)192 * K), dst + 12288);
    };
    auto stageB = [&](int u) {   // full B tile(s) of K-tile u (4 loads/thread)
        bf16_t* dst = &lds[(u & 1) * 32768 + 16384 + wave * 512];
        const bf16_t* src = B1g + ((size_t)u << 6);
        gload16(src,                    dst);
        gload16(src + ((size_t)64 * K), dst + 4096);
        if constexpr (DUAL) {
            bf16_t* dst2 = &lds[(u & 1) * 32768 + 24576 + wave * 512];
            const bf16_t* src2 = B2g + ((size_t)u << 6);
            gload16(src2,                    dst2);
            gload16(src2 + ((size_t)64 * K), dst2 + 4096);
        } else {
            gload16(src + ((size_t)128 * K), dst + 8192);
            gload16(src + ((size_t)192 * K), dst + 12288);
        }
    };
    auto rdA = [&](int p, int m, int ks) {
        const int row = wr * 128 + m * 16 + lr16;
        const int c = ks * 4 + lk;
        return *(const bf16x8*)&lds[p * 32768 + row * 64 + (((c ^ row) & 7) << 3)];
    };
    auto rdB = [&](int p, int mat, int n, int ks) {
        const int row = wc * (BN / 4) + n * 16 + lr16;
        const int c = ks * 4 + lk;
        return *(const bf16x8*)&lds[p * 32768 + 16384 + mat * 8192 + row * 64 +
                                    (((c ^ row) & 7) << 3)];
    };

    // prologue: stage tile 0, drain, sync
    stageA(0);
    stageB(0);
    asm volatile("s_waitcnt vmcnt(0)" ::: "memory");
    __builtin_amdgcn_s_barrier();

    for (int t = 0; t < nt; ++t) {
        const int p = t & 1;
        const bool pre = (t + 1 < nt);
        bf16x8 bF[DUAL ? 2 : 1][NFR];
        bf16x8 aF[4];

        // ---- phase 0: ks=0 | read B(ks0)+A(m0-3,ks0) | stage A(t+1) ----
#pragma unroll
        for (int n = 0; n < NFR; ++n) {
            bF[0][n] = rdB(p, 0, n, 0);
            if constexpr (DUAL) bF[1][n] = rdB(p, 1, n, 0);
        }
#pragma unroll
        for (int m = 0; m < 4; ++m) aF[m] = rdA(p, m, 0);
        if (pre) stageA(t + 1);
        __builtin_amdgcn_s_barrier();
        asm volatile("s_waitcnt lgkmcnt(0)" ::: "memory");
        __builtin_amdgcn_sched_barrier(0);
        __builtin_amdgcn_s_setprio(1);
#pragma unroll
        for (int m = 0; m < 4; ++m)
#pragma unroll
            for (int n = 0; n < NFR; ++n) {
                acc1[m][n] = MFMA16(aF[m], bF[0][n], acc1[m][n]);
                if constexpr (DUAL) acc2[m][n] = MFMA16(aF[m], bF[1][n], acc2[m][n]);
            }
        __builtin_amdgcn_s_setprio(0);
        __builtin_amdgcn_s_barrier();

        // ---- phase 1: ks=0 | read A(m4-7,ks0) | stage B(t+1) ----
#pragma unroll
        for (int m = 0; m < 4; ++m) aF[m] = rdA(p, 4 + m, 0);
        if (pre) stageB(t + 1);
        __builtin_amdgcn_s_barrier();
        asm volatile("s_waitcnt lgkmcnt(0)" ::: "memory");
        __builtin_amdgcn_sched_barrier(0);
        __builtin_amdgcn_s_setprio(1);
#pragma unroll
        for (int m = 0; m < 4; ++m)
#pragma unroll
            for (int n = 0; n < NFR; ++n) {
                acc1[4 + m][n] = MFMA16(aF[m], bF[0][n], acc1[4 + m][n]);
                if constexpr (DUAL) acc2[4 + m][n] = MFMA16(aF[m], bF[1][n], acc2[4 + m][n]);
            }
        __builtin_amdgcn_s_setprio(0);
        __builtin_amdgcn_s_barrier();

        // ---- phase 2: ks=1 | read B(ks1)+A(m0-3,ks1) ----
#pragma unroll
        for (int n = 0; n < NFR; ++n) {
            bF[0][n] = rdB(p, 0, n, 1);
            if constexpr (DUAL) bF[1][n] = rdB(p, 1, n, 1);
        }
#pragma unroll
        for (int m = 0; m < 4; ++m) aF[m] = rdA(p, m, 1);
        __builtin_amdgcn_s_barrier();
        asm volatile("s_waitcnt lgkmcnt(0)" ::: "memory");
        __builtin_amdgcn_sched_barrier(0);
        __builtin_amdgcn_s_setprio(1);
#pragma unroll
        for (int m = 0; m < 4; ++m)
#pragma unroll
            for (int n = 0; n < NFR; ++n) {
                acc1[m][n] = MFMA16(aF[m], bF[0][n], acc1[m][n]);
                if constexpr (DUAL) acc2[m][n] = MFMA16(aF[m], bF[1][n], acc2[m][n]);
            }
        __builtin_amdgcn_s_setprio(0);
        __builtin_amdgcn_s_barrier();

        // ---- phase 3: ks=1 | read A(m4-7,ks1) | tile-boundary drain ----
#pragma unroll
        for (int m = 0; m < 4; ++m) aF[m] = rdA(p, 4 + m, 1);
        __builtin_amdgcn_s_barrier();
        asm volatile("s_waitcnt lgkmcnt(0)" ::: "memory");
        __builtin_amdgcn_sched_barrier(0);
        __builtin_amdgcn_s_setprio(1);
#pragma unroll
        for (int m = 0; m < 4; ++m)
#pragma unroll
            for (int n = 0; n < NFR; ++n) {
                acc1[4 + m][n] = MFMA16(aF[m], bF[0][n], acc1[4 + m][n]);
                if constexpr (DUAL) acc2[4 + m][n] = MFMA16(aF[m], bF[1][n], acc2[4 + m][n]);
            }
        __builtin_amdgcn_s_setprio(0);
        asm volatile("s_waitcnt vmcnt(0)" ::: "memory");  // t+1 fully in LDS
        __builtin_amdgcn_s_barrier();
    }

    // ---- epilogue ----
    const int rowBase = bm * 256 + wr * 128;
    const int colBase = bn * BN + wc * (BN / 4);
#pragma unroll
    for (int n = 0; n < NFR; ++n) {
        const int col = colBase + n * 16 + lr16;
        float b1v = 0.f, b2v = 0.f;
        if constexpr (MODE == 0) { b1v = bias1[col]; b2v = bias2[col]; }
#pragma unroll
        for (int m = 0; m < 8; ++m) {
#pragma unroll
            for (int j = 0; j < 4; ++j) {
                const int row = rowBase + m * 16 + lk * 4 + j;
                const size_t idx = (size_t)row * N + col;
                if constexpr (MODE == 0) {
                    const float gv = 1.0f / (1.0f + __expf(-(acc1[m][n][j] + b1v)));
                    const float cv = tanhf(acc2[m][n][j] + b2v);
                    bf16x2 pk;
                    pk[0] = (bf16_t)gv;
                    pk[1] = (bf16_t)cv;
                    GC[idx] = pk;
                } else if constexpr (MODE == 1) {
                    const float a = acc1[m][n][j];
                    const float s = a / (1.0f + __expf(-a));
                    Ot[idx] = (bf16_t)(s * acc2[m][n][j]);
                } else {
                    O[idx] += acc1[m][n][j];
                }
            }
        }
    }
}

// ---------------------------------------------------------------------------
// MinGRU scan: h_t = g_t*h_{t-1} + (1-g_t)*c_t, chunked 3-phase.
// gc: [BATCH][SEQ][D_MODEL] packed bf16x2 {g, c}.
// ---------------------------------------------------------------------------
__global__ void scan_phase1(const bf16x2* __restrict__ gc,
                            float* __restrict__ cA, float* __restrict__ cB) {
    const int d = blockIdx.x * 256 + threadIdx.x;
    const int b = blockIdx.y;
    const int cidx = blockIdx.z;
    const int ch = b * D_MODEL + d;
    const size_t base = ((size_t)b * SEQ + (size_t)cidx * CLEN) * D_MODEL + d;
    float A = 1.0f, Bv = 0.0f;
#pragma unroll 8
    for (int t = 0; t < CLEN; ++t) {
        const bf16x2 v = gc[base + (size_t)t * D_MODEL];
        const float gv = (float)v[0], cv = (float)v[1];
        Bv = gv * Bv + (1.0f - gv) * cv;
        A *= gv;
    }
    cA[cidx * NCH + ch] = A;
    cB[cidx * NCH + ch] = Bv;
}

__global__ void scan_phase2(const float* __restrict__ cA,
                            const float* __restrict__ cB,
                            float* __restrict__ hstart) {
    const int ch = blockIdx.x * 256 + threadIdx.x;
    float h = 0.0f;
#pragma unroll 8
    for (int cdx = 0; cdx < NCHUNK; ++cdx) {
        hstart[cdx * NCH + ch] = h;
        h = cA[cdx * NCH + ch] * h + cB[cdx * NCH + ch];
    }
}

__global__ void scan_phase3(const bf16x2* __restrict__ gc,
                            const float* __restrict__ hstart,
                            const float* __restrict__ x,
                            float* __restrict__ x1) {
    const int d = blockIdx.x * 256 + threadIdx.x;
    const int b = blockIdx.y;
    const int cidx = blockIdx.z;
    const int ch = b * D_MODEL + d;
    const size_t base = ((size_t)b * SEQ + (size_t)cidx * CLEN) * D_MODEL + d;
    float h = hstart[cidx * NCH + ch];
#pragma unroll 8
    for (int t = 0; t < CLEN; ++t) {
        const size_t off = base + (size_t)t * D_MODEL;
        const bf16x2 v = gc[off];
        const float gv = (float)v[0], cv = (float)v[1];
        h = gv * h + (1.0f - gv) * cv;
        x1[off] = x[off] + h;
    }
}

// ---------------------------------------------------------------------------
extern "C" void kernel_launch(void* const* d_in, const int* in_sizes, int n_in,
                              void* d_out, int out_size, void* d_ws,
                              size_t ws_size, hipStream_t stream) {
    const float* x   = (const float*)d_in[0];
    const float* Wg  = (const float*)d_in[1];
    const float* bg  = (const float*)d_in[2];
    const float* Wc  = (const float*)d_in[3];
    const float* bc  = (const float*)d_in[4];
    const float* n1w = (const float*)d_in[5];
    const float* n2w = (const float*)d_in[6];
    const float* W1  = (const float*)d_in[7];
    const float* W3  = (const float*)d_in[8];
    const float* W2  = (const float*)d_in[9];
    float* out = (float*)d_out;

    // Workspace layout (191 MB total; tbuf overlaps h_in+gcbuf+pad, all of
    // which are dead by the time the FFN dual GEMM writes tbuf):
    char* p = (char*)d_ws;
    bf16_t* tbuf  = (bf16_t*)p;                        // 128 MB [0,128)
    bf16_t* h_in  = (bf16_t*)p;  p += (size_t)NTOK * D_MODEL * 2;   // 32 MB
    bf16x2* gcbuf = (bf16x2*)p;  p += (size_t)NTOK * D_MODEL * 4;   // 64 MB
    p += (size_t)32 << 20;                             // pad (tail of tbuf)
    bf16_t* f_in  = (bf16_t*)p;  p += (size_t)NTOK * D_MODEL * 2;   // 32 MB
    bf16_t* Wg_t  = (bf16_t*)p;  p += (size_t)D_MODEL * D_MODEL * 2;
    bf16_t* Wc_t  = (bf16_t*)p;  p += (size_t)D_MODEL * D_MODEL * 2;
    bf16_t* W1_t  = (bf16_t*)p;  p += (size_t)DFF * D_MODEL * 2;
    bf16_t* W3_t  = (bf16_t*)p;  p += (size_t)DFF * D_MODEL * 2;
    bf16_t* W2_t  = (bf16_t*)p;  p += (size_t)D_MODEL * DFF * 2;
    float* cA     = (float*)p;   p += (size_t)NCHUNK * NCH * 4;
    float* cB     = (float*)p;   p += (size_t)NCHUNK * NCH * 4;
    float* hstart = (float*)p;   p += (size_t)NCHUNK * NCH * 4;

    const dim3 tb(32, 8);
    transpose_to_bf16<<<dim3(1024 / 32, 1024 / 32), tb, 0, stream>>>(Wg, Wg_t, 1024, 1024);
    transpose_to_bf16<<<dim3(1024 / 32, 1024 / 32), tb, 0, stream>>>(Wc, Wc_t, 1024, 1024);
    transpose_to_bf16<<<dim3(4096 / 32, 1024 / 32), tb, 0, stream>>>(W1, W1_t, 1024, 4096);
    transpose_to_bf16<<<dim3(4096 / 32, 1024 / 32), tb, 0, stream>>>(W3, W3_t, 1024, 4096);
    transpose_to_bf16<<<dim3(1024 / 32, 4096 / 32), tb, 0, stream>>>(W2, W2_t, 4096, 1024);

    // 1) h_in = rmsnorm(x, n1_w)  (bf16)
    rmsnorm_kernel<<<NTOK, 256, 0, stream>>>(x, n1w, h_in);

    // 2) gc = {sigmoid(h_in@Wg+bg), tanh(h_in@Wc+bc)} packed bf16x2
    //    grid = (M/256)*(N/128) = 64*8 = 512 blocks, lg_nbn = 3
    gemm8p<0><<<512, 512, 0, stream>>>(h_in, Wg_t, Wc_t, bg, bc, gcbuf,
                                       nullptr, nullptr, D_MODEL, D_MODEL, 3);

    // 3) chunked scan; phase3 writes x1 = x + h into d_out
    scan_phase1<<<dim3(D_MODEL / 256, BATCH, NCHUNK), 256, 0, stream>>>(gcbuf, cA, cB);
    scan_phase2<<<NCH / 256, 256, 0, stream>>>(cA, cB, hstart);
    scan_phase3<<<dim3(D_MODEL / 256, BATCH, NCHUNK), 256, 0, stream>>>(gcbuf, hstart, x, out);

    // 4) f_in = rmsnorm(x1, n2_w)
    rmsnorm_kernel<<<NTOK, 256, 0, stream>>>(out, n2w, f_in);

    // 5) t = silu(f_in@W1) * (f_in@W3)  (bf16)
    //    grid = 64 * (4096/128=32) = 2048 blocks, lg_nbn = 5
    gemm8p<1><<<2048, 512, 0, stream>>>(f_in, W1_t, W3_t, nullptr, nullptr,
                                        nullptr, tbuf, nullptr, DFF, D_MODEL, 5);

    // 6) out = x1 + t@W2  (in-place on d_out)
    //    grid = 64 * (1024/256=4) = 256 blocks, lg_nbn = 2
    gemm8p<2><<<256, 512, 0, stream>>>(tbuf, W2_t, nullptr, nullptr, nullptr,
                                       nullptr, nullptr, out, D_MODEL, DFF, 2);
}